// Round 9
// baseline (231.782 us; speedup 1.0000x reference)
//
#include <hip/hip_runtime.h>
#include <math.h>

typedef _Float16 f16;
typedef _Float16 f16x8 __attribute__((ext_vector_type(8)));
typedef float f32x4 __attribute__((ext_vector_type(4)));

#define Bn 128
#define Tn 32
#define Hn 768
#define En 4
#define Fn 3072
#define Rn 256

static constexpr size_t OUT_ELEMS  = (size_t)Rn*Tn*Hn;
static constexpr size_t SCORES_OFF = OUT_ELEMS;
static constexpr size_t ROUTE_OFF  = OUT_ELEMS + Rn;
static constexpr size_t BIDX_OFF   = OUT_ELEMS + 2*Rn;
static constexpr size_t LOSS_OFF   = OUT_ELEMS + 3*Rn;

// ws byte offsets
#define WS_WSF    0u
#define WS_ROUTE  4096u
#define WS_GRP    8192u
#define WS_X16    16384u
#define WS_W1T    (WS_X16 + 2u*Bn*Tn*Hn)
#define WS_W2T    (WS_W1T + 2u*En*Hn*Fn)
#define WS_H1     (WS_W2T + 2u*En*Fn*Hn)

#define GLOAD16(g, l) __builtin_amdgcn_global_load_lds( \
    (const __attribute__((address_space(1))) unsigned int*)(g), \
    (__attribute__((address_space(3))) unsigned int*)(l), 16, 0, 0)

__device__ __forceinline__ float fast_gelu(float v) {
  float s = v * 0.70710678118f;
  float a = fabsf(s);
  float t = 1.0f / (1.0f + 0.3275911f * a);
  float y = t*(0.254829592f + t*(-0.284496736f + t*(1.421413741f +
            t*(-1.453152027f + t*1.061405429f))));
  float er = 1.0f - y * __expf(-a*a);
  er = (s < 0.0f) ? -er : er;
  return 0.5f * v * (1.0f + er);
}

// 4-wave gate: fused x->fp16 conversion + gating logits + softmax + top2.
__global__ __launch_bounds__(256) void gate_kernel(
    const float* __restrict__ x, const float* __restrict__ Wg,
    float* __restrict__ out, float* __restrict__ wsf, int* __restrict__ route,
    f16* __restrict__ x16)
{
  const int b = blockIdx.x;
  const int tid = threadIdx.x;
  const int w = tid >> 6, l = tid & 63;
  __shared__ float pacc[4][4];
  float a0=0.f, a1=0.f, a2=0.f, a3=0.f;
  const float* xb = x   + (size_t)b*Tn*Hn + (size_t)(w*8)*Hn;
  f16*         xh = x16 + (size_t)b*Tn*Hn + (size_t)(w*8)*Hn;
  #pragma unroll
  for (int k = 0; k < 12; ++k) {
    const int h = l + 64*k;
    const float w0 = Wg[0*Hn+h], w1 = Wg[1*Hn+h], w2 = Wg[2*Hn+h], w3 = Wg[3*Hn+h];
    #pragma unroll
    for (int t = 0; t < 8; ++t) {
      float v = xb[t*Hn + h];
      xh[t*Hn + h] = (f16)v;
      a0 += v*w0; a1 += v*w1; a2 += v*w2; a3 += v*w3;
    }
  }
  #pragma unroll
  for (int o = 32; o > 0; o >>= 1) {
    a0 += __shfl_down(a0,o); a1 += __shfl_down(a1,o);
    a2 += __shfl_down(a2,o); a3 += __shfl_down(a3,o);
  }
  if (l == 0) { pacc[w][0]=a0; pacc[w][1]=a1; pacc[w][2]=a2; pacc[w][3]=a3; }
  __syncthreads();
  if (tid == 0) {
    float lg[4];
    #pragma unroll
    for (int e = 0; e < 4; ++e)
      lg[e] = (pacc[0][e]+pacc[1][e]+pacc[2][e]+pacc[3][e]) * (1.0f/Tn);
    float m = fmaxf(fmaxf(lg[0],lg[1]), fmaxf(lg[2],lg[3]));
    float p[4]; float s = 0.f;
    #pragma unroll
    for (int e = 0; e < 4; ++e) { p[e] = expf(lg[e]-m); s += p[e]; }
    float inv = 1.f/s;
    #pragma unroll
    for (int e = 0; e < 4; ++e) { p[e] *= inv; wsf[b*4+e] = p[e]; }
    int i1 = 0;
    #pragma unroll
    for (int e = 1; e < 4; ++e) if (p[e] > p[i1]) i1 = e;
    int i2 = (i1 == 0) ? 1 : 0;
    #pragma unroll
    for (int e = 0; e < 4; ++e) if (e != i1 && p[e] > p[i2]) i2 = e;
    int idx[2] = {i1, i2};
    #pragma unroll
    for (int k = 0; k < 2; ++k) {
      int r = 2*b + k;
      float pv = p[idx[k]];
      wsf[512 + r] = pv;
      route[r] = idx[k];
      out[SCORES_OFF + r] = pv;
      out[ROUTE_OFF  + r] = (float)idx[k];
      out[BIDX_OFF   + r] = (float)r;
    }
  }
}

__global__ __launch_bounds__(64) void loss_kernel(
    const float* __restrict__ wsf, float* __restrict__ out)
{
  const int l = threadIdx.x;
  float i0=0.f,i1=0.f,i2=0.f,i3=0.f;
  for (int b = l; b < Bn; b += 64) {
    i0 += wsf[b*4+0]; i1 += wsf[b*4+1]; i2 += wsf[b*4+2]; i3 += wsf[b*4+3];
  }
  #pragma unroll
  for (int o = 32; o > 0; o >>= 1) {
    i0 += __shfl_down(i0,o); i1 += __shfl_down(i1,o);
    i2 += __shfl_down(i2,o); i3 += __shfl_down(i3,o);
  }
  if (l == 0) {
    float mean = 0.25f*(i0+i1+i2+i3);
    float d0=i0-mean, d1=i1-mean, d2=i2-mean, d3=i3-mean;
    float var = (d0*d0+d1*d1+d2*d2+d3*d3) * (1.f/3.f);
    out[LOSS_OFF] = var / (mean*mean);
  }
}

// grp: [0]=nt4; tiles at [8+3i]={e,bstart,nb<=4}; blist at [384..639]
__global__ __launch_bounds__(64) void group_kernel(
    const int* __restrict__ route, int* __restrict__ grp)
{
  const int l = threadIdx.x;
  int cnt = 0;
  if (l < 4) { for (int r = 0; r < Rn; ++r) cnt += (route[r] == l); }
  int c0 = __shfl(cnt, 0), c1 = __shfl(cnt, 1), c2 = __shfl(cnt, 2), c3 = __shfl(cnt, 3);
  int off = (l >= 1 ? c0 : 0) + (l >= 2 ? c1 : 0) + (l >= 3 ? c2 : 0);
  if (l < 4) {
    int p = off;
    for (int r = 0; r < Rn; ++r) if (route[r] == l) grp[384 + p++] = r;
  }
  if (l == 0) {
    int cs[4] = {c0, c1, c2, c3};
    int os[4] = {0, c0, c0+c1, c0+c1+c2};
    int nt4 = 0;
    for (int e = 0; e < 4; ++e) {
      for (int s = 0; s < cs[e]; s += 4) {
        int nb = cs[e] - s; if (nb > 4) nb = 4;
        grp[8+nt4*3+0] = e; grp[8+nt4*3+1] = os[e]+s; grp[8+nt4*3+2] = nb;
        ++nt4;
      }
    }
    grp[0] = nt4;
  }
}

// Merged transpose+convert for W1 and W2: flat grid of 64x64 tiles.
// bid<2304 -> W1 (R=768,C=3072); else W2 (R=3072,C=768). 576 tiles/expert each.
__global__ __launch_bounds__(256) void transcvt_kernel(
    const float* __restrict__ W1s, const float* __restrict__ W2s,
    f16* __restrict__ d1, f16* __restrict__ d2)
{
  __shared__ f16 t[64][74];
  int bid = blockIdx.x;
  const float* s; f16* d; int R, C, rc;
  if (bid < 2304) { s = W1s; d = d1; R = Hn; C = Fn; rc = bid; }
  else            { s = W2s; d = d2; R = Fn; C = Hn; rc = bid - 2304; }
  const int e = rc / 576; rc -= e*576;
  const int nx = C >> 6;
  const int cy = rc / nx, cx = rc - cy*nx;
  const int r0 = cy*64, c0 = cx*64;
  s += (size_t)e*R*C;
  d += (size_t)e*R*C;
  const int tid = threadIdx.x;
  const int i  = tid >> 2;
  const int j0 = (tid & 3) * 16;
  #pragma unroll
  for (int q = 0; q < 16; q += 4) {
    float4 v = *(const float4*)(s + (size_t)(r0+i)*C + c0 + j0 + q);
    t[i][j0+q+0]=(f16)v.x; t[i][j0+q+1]=(f16)v.y; t[i][j0+q+2]=(f16)v.z; t[i][j0+q+3]=(f16)v.w;
  }
  __syncthreads();
  f16 o[16];
  #pragma unroll
  for (int q = 0; q < 16; ++q) o[q] = t[j0+q][i];
  *(uint4*)(d + (size_t)(c0+i)*R + r0 + j0)     = *(uint4*)&o[0];
  *(uint4*)(d + (size_t)(c0+i)*R + r0 + j0 + 8) = *(uint4*)&o[8];
}

// ---------------------------------------------------------------------------
// Grouped GEMM, m201-style schedule: BM=128, BK=64, wave-tile 64x64,
// 2 phases/K-tile of {8 ds_read_b128 ; (stage/vm) ; barrier ; lgkm0 ; 16 MFMA ;
// (vm) ; barrier}.  NBUF=3 (depth-2, vmcnt(NLD)) or NBUF=2 (depth-1, vmcnt(0)).
// Persistent blocks over jobs (tix,ny), contiguous chunks for A-panel reuse.
// LDS buffer: A[128][128B] then B[BN][128B]; 3-bit XOR unit swizzle both-sides.
// ---------------------------------------------------------------------------
template<int KD, int ND, int BN, int NWAVE, int NBUF, bool G1>
__global__ __launch_bounds__(NWAVE*64, 2) void gemm_kernel(
    const f16* __restrict__ A16, const f16* __restrict__ B16,
    const float* __restrict__ bias, f16* __restrict__ oh,
    float* __restrict__ of, const int* __restrict__ grp,
    const float* __restrict__ wsf)
{
  constexpr int NWY  = BN / 64;
  constexpr int NY   = ND / BN;
  constexpr int NT   = KD / 64;
  constexpr int GL_A = 1024 / (NWAVE*64);       // A gloads/thread/K-tile
  constexpr int GL_B = (BN*8) / (NWAVE*64);     // B gloads/thread/K-tile
  constexpr int NLD  = GL_A + GL_B;
  constexpr int BUFSZ = (128 + BN) * 128;
  constexpr int PRE_D = NBUF - 1;               // staging depth
  constexpr int TPR  = NWAVE*2;                 // store rows per iteration
  static_assert(NT % NBUF == 0, "NT % NBUF");

  const int ntiles = grp[0];
  const int njobs  = ntiles * NY;
  const int tid  = threadIdx.x;
  const int lane = tid & 63;
  const int w    = tid >> 6;

  extern __shared__ __align__(16) char smem[];

  // fragment geometry (job-independent)
  const int wm = w / NWY, wn = w % NWY;
  const int lr = lane & 15, lk = lane >> 4;
  const int rowA0 = wm*64;
  const int rowB0 = wn*64;
  const int r7 = lr & 7;
  const int ub[2] = { ((lk) ^ r7) << 4, ((4+lk) ^ r7) << 4 };

  const int j0 = (int)(((long long)blockIdx.x     * njobs) / gridDim.x);
  const int j1 = (int)(((long long)(blockIdx.x+1) * njobs) / gridDim.x);

  for (int job = j0; job < j1; ++job) {
    const int tix = job / NY;
    const int ny  = job - tix*NY;
    const int e      = grp[8+tix*3+0];
    const int bstart = grp[8+tix*3+1];
    const int nb     = grp[8+tix*3+2];
    const int n0     = ny * BN;

    // ---- staging sources (pre-swizzled: LDS unit cu holds global unit cu^(row&7)) ----
    const f16* asrc[GL_A];
    #pragma unroll
    for (int i = 0; i < GL_A; ++i) {
      const int U   = (w*GL_A + i)*64 + lane;
      const int row = U >> 3;
      const int gu  = (U & 7) ^ (row & 7);
      int slot = row >> 5; if (slot >= nb) slot = nb - 1;
      const int beam = grp[384 + bstart + slot];
      const size_t rbase = (G1 ? (size_t)(beam>>1)*Tn : (size_t)beam*Tn) + (row & 31);
      asrc[i] = A16 + rbase*(size_t)KD + gu*8;
    }
    const f16* bsrc[GL_B];
    #pragma unroll
    for (int i = 0; i < GL_B; ++i) {
      const int U   = (w*GL_B + i)*64 + lane;
      const int row = U >> 3;
      const int gu  = (U & 7) ^ (row & 7);
      bsrc[i] = B16 + (size_t)e*ND*KD + (size_t)(n0 + row)*KD + gu*8;
    }

    f32x4 acc[4][4];
    #pragma unroll
    for (int i=0;i<4;++i)
      #pragma unroll
      for (int j=0;j<4;++j) acc[i][j] = (f32x4){0.f,0.f,0.f,0.f};

    auto STAGE = [&](int bsel, int kt2) {
      char* Ad = smem + bsel*BUFSZ + (w*GL_A)*1024;
      #pragma unroll
      for (int i = 0; i < GL_A; ++i) GLOAD16(asrc[i] + kt2*64, Ad + i*1024);
      char* Bd = smem + bsel*BUFSZ + 128*128 + (w*GL_B)*1024;
      #pragma unroll
      for (int i = 0; i < GL_B; ++i) GLOAD16(bsrc[i] + kt2*64, Bd + i*1024);
    };

    // phase: ds_reads ; PRE ; barrier ; lgkm0 ; prio1 ; 16 MFMA ; prio0 ; POST ; barrier
#define PHASE(BUFI, KS, PRE, POST) do {                                        \
      const char* Ab_ = smem + (BUFI)*BUFSZ;                                   \
      const char* Bb_ = Ab_ + 128*128;                                         \
      f16x8 af[4], bf[4];                                                      \
      _Pragma("unroll")                                                        \
      for (int mi=0;mi<4;++mi)                                                 \
        af[mi] = *(const f16x8*)(Ab_ + (rowA0+mi*16+lr)*128 + ub[KS]);         \
      _Pragma("unroll")                                                        \
      for (int ni=0;ni<4;++ni)                                                 \
        bf[ni] = *(const f16x8*)(Bb_ + (rowB0+ni*16+lr)*128 + ub[KS]);         \
      PRE;                                                                     \
      __builtin_amdgcn_s_barrier();                                            \
      __builtin_amdgcn_sched_barrier(0);                                       \
      asm volatile("s_waitcnt lgkmcnt(0)" ::: "memory");                       \
      __builtin_amdgcn_sched_barrier(0);                                       \
      __builtin_amdgcn_s_setprio(1);                                           \
      _Pragma("unroll")                                                        \
      for (int mi=0;mi<4;++mi)                                                 \
        _Pragma("unroll")                                                      \
        for (int ni=0;ni<4;++ni)                                               \
          acc[mi][ni] = __builtin_amdgcn_mfma_f32_16x16x32_f16(af[mi], bf[ni], acc[mi][ni], 0, 0, 0); \
      __builtin_amdgcn_s_setprio(0);                                           \
      POST;                                                                    \
      __builtin_amdgcn_s_barrier();                                            \
      __builtin_amdgcn_sched_barrier(0);                                       \
    } while (0)

#define TILE(BUFI, KT) do {                                                    \
      PHASE(BUFI, 0,                                                           \
            { if ((KT)+PRE_D < NT) STAGE(((BUFI)+PRE_D)%NBUF, (KT)+PRE_D); },  \
            {});                                                               \
      PHASE(BUFI, 1, {},                                                       \
            { if (PRE_D == 2 && (KT)+2 < NT) {                                 \
                asm volatile("s_waitcnt vmcnt(%0)" :: "i"(NLD) : "memory");    \
              } else if ((KT)+1 < NT) {                                        \
                asm volatile("s_waitcnt vmcnt(0)" ::: "memory");               \
              }                                                                \
              __builtin_amdgcn_sched_barrier(0); });                           \
    } while (0)

    // prologue: stage tiles 0..PRE_D-1, certify tile 0
    STAGE(0, 0);
    if (PRE_D == 2) {
      STAGE(1, 1);
      asm volatile("s_waitcnt vmcnt(%0)" :: "i"(NLD) : "memory");
    } else {
      asm volatile("s_waitcnt vmcnt(0)" ::: "memory");
    }
    __builtin_amdgcn_sched_barrier(0);
    __builtin_amdgcn_s_barrier();
    __builtin_amdgcn_sched_barrier(0);

    if constexpr (NBUF == 3) {
      for (int kt = 0; kt < NT; kt += 3) {
        TILE(0, kt);
        TILE(1, kt+1);
        TILE(2, kt+2);
      }
    } else {
      for (int kt = 0; kt < NT; kt += 2) {
        TILE(0, kt);
        TILE(1, kt+1);
      }
    }
#undef TILE
#undef PHASE

    // ---- epilogue: 128 rows through swizzled LDS (64 KB) ----
    const int nvalid = nb * Tn;
    char* cst = smem;
    float bvals[4];
    if (G1) {
      #pragma unroll
      for (int ni=0;ni<4;++ni) bvals[ni] = bias[e*ND + n0 + rowB0 + ni*16 + lr];
    }
    #pragma unroll
    for (int mi=0;mi<4;++mi){
      #pragma unroll
      for (int j=0;j<4;++j){
        const int m = rowA0 + mi*16 + (lane>>4)*4 + j;
        const int m7 = m & 7;
        #pragma unroll
        for (int ni=0;ni<4;++ni){
          const int n = rowB0 + ni*16 + lr;
          if (G1) {
            float v = acc[mi][ni][j] + bvals[ni];
            *(f16*)(cst + m*512 + (((n>>3)^m7)<<4) + (n&7)*2) = (f16)fast_gelu(v);
          } else {
            *(float*)(cst + m*512 + (((n>>2)^m7)<<4) + (n&3)*4) = acc[mi][ni][j];
          }
        }
      }
    }
    __syncthreads();
    {
      const int u  = tid & 31;
      const int tr = tid >> 5;
      float4 b4;
      if (!G1) b4 = *(const float4*)(bias + e*ND + n0 + u*4);
      #pragma unroll
      for (int it = 0; it < 128/TPR; ++it) {
        const int rl = it*TPR + tr;
        if (rl < nvalid) {
          const int beam = grp[384 + bstart + (rl>>5)];
          if (G1) {
            uint4 v = *(const uint4*)(cst + rl*512 + (((u&24)|((u&7)^(rl&7)))<<4));
            *(uint4*)(oh + ((size_t)beam*Tn + (rl&31))*(size_t)ND + n0 + u*8) = v;
          } else {
            const float sc = wsf[512 + beam];
            float4 v = *(const float4*)(cst + rl*512 + (((u&24)|((u&7)^(rl&7)))<<4));
            v.x = (v.x + b4.x)*sc; v.y = (v.y + b4.y)*sc;
            v.z = (v.z + b4.z)*sc; v.w = (v.w + b4.w)*sc;
            *(float4*)(of + ((size_t)beam*Tn + (rl&31))*(size_t)Hn + n0 + u*4) = v;
          }
        }
      }
    }
    __syncthreads();   // cst dead before next job's STAGE
  }
}

extern "C" void kernel_launch(void* const* d_in, const int* in_sizes, int n_in,
                              void* d_out, int out_size, void* d_ws, size_t ws_size,
                              hipStream_t stream)
{
  const float* x  = (const float*)d_in[0];
  const float* Wg = (const float*)d_in[1];
  const float* W1 = (const float*)d_in[2];
  const float* b1 = (const float*)d_in[3];
  const float* W2 = (const float*)d_in[4];
  const float* b2 = (const float*)d_in[5];
  float* out = (float*)d_out;
  char* ws = (char*)d_ws;
  float* wsf  = (float*)(ws + WS_WSF);
  int*   route= (int*)(ws + WS_ROUTE);
  int*   grp  = (int*)(ws + WS_GRP);
  f16*   x16  = (f16*)(ws + WS_X16);
  f16*   w1t  = (f16*)(ws + WS_W1T);
  f16*   w2t  = (f16*)(ws + WS_W2T);
  f16*   h1   = (f16*)(ws + WS_H1);

  gate_kernel<<<Bn, 256, 0, stream>>>(x, Wg, out, wsf, route, x16);
  group_kernel<<<1, 64, 0, stream>>>(route, grp);
  loss_kernel<<<1, 64, 0, stream>>>(wsf, out);
  transcvt_kernel<<<4608, 256, 0, stream>>>(W1, W2, w1t, w2t);

  auto g1 = gemm_kernel<Hn, Fn, 256, 8, 3, true>;    // 512 thr, LDS 144KB, 1 blk/CU
  auto g2 = gemm_kernel<Fn, Hn, 128, 4, 2, false>;   // 256 thr, LDS 64KB,  2 blk/CU
  const int sm1 = 3 * (128 + 256) * 128;   // 147456
  const int sm2 = 2 * (128 + 128) * 128;   // 65536
  hipFuncSetAttribute((const void*)g1, hipFuncAttributeMaxDynamicSharedMemorySize, sm1);
  hipFuncSetAttribute((const void*)g2, hipFuncAttributeMaxDynamicSharedMemorySize, sm2);
  g1<<<256, 512, sm1, stream>>>(x16, w1t, b1, h1, nullptr, grp, wsf);
  g2<<<512, 256, sm2, stream>>>(h1, w2t, b2, nullptr, out, grp, wsf);
}

// Round 10
// 204.658 us; speedup vs baseline: 1.1325x; 1.1325x over previous
//
#include <hip/hip_runtime.h>
#include <math.h>

typedef _Float16 f16;
typedef _Float16 f16x8 __attribute__((ext_vector_type(8)));
typedef float f32x4 __attribute__((ext_vector_type(4)));

#define Bn 128
#define Tn 32
#define Hn 768
#define En 4
#define Fn 3072
#define Rn 256
#define MAXT4 67

static constexpr size_t OUT_ELEMS  = (size_t)Rn*Tn*Hn;
static constexpr size_t SCORES_OFF = OUT_ELEMS;
static constexpr size_t ROUTE_OFF  = OUT_ELEMS + Rn;
static constexpr size_t BIDX_OFF   = OUT_ELEMS + 2*Rn;
static constexpr size_t LOSS_OFF   = OUT_ELEMS + 3*Rn;

// ws byte offsets
#define WS_WSF    0u
#define WS_ROUTE  4096u
#define WS_GRP    8192u
#define WS_X16    16384u
#define WS_W1T    (WS_X16 + 2u*Bn*Tn*Hn)
#define WS_W2T    (WS_W1T + 2u*En*Hn*Fn)
#define WS_H1     (WS_W2T + 2u*En*Fn*Hn)

#define GLOAD16(g, l) __builtin_amdgcn_global_load_lds( \
    (const __attribute__((address_space(1))) unsigned int*)(g), \
    (__attribute__((address_space(3))) unsigned int*)(l), 16, 0, 0)

__device__ __forceinline__ float fast_gelu(float v) {
  float s = v * 0.70710678118f;
  float a = fabsf(s);
  float t = 1.0f / (1.0f + 0.3275911f * a);
  float y = t*(0.254829592f + t*(-0.284496736f + t*(1.421413741f +
            t*(-1.453152027f + t*1.061405429f))));
  float er = 1.0f - y * __expf(-a*a);
  er = (s < 0.0f) ? -er : er;
  return 0.5f * v * (1.0f + er);
}

// 4-wave gate: fused x->fp16 conversion + gating logits + softmax + top2.
__global__ __launch_bounds__(256) void gate_kernel(
    const float* __restrict__ x, const float* __restrict__ Wg,
    float* __restrict__ out, float* __restrict__ wsf, int* __restrict__ route,
    f16* __restrict__ x16)
{
  const int b = blockIdx.x;
  const int tid = threadIdx.x;
  const int w = tid >> 6, l = tid & 63;
  __shared__ float pacc[4][4];
  float a0=0.f, a1=0.f, a2=0.f, a3=0.f;
  const float* xb = x   + (size_t)b*Tn*Hn + (size_t)(w*8)*Hn;
  f16*         xh = x16 + (size_t)b*Tn*Hn + (size_t)(w*8)*Hn;
  #pragma unroll
  for (int k = 0; k < 12; ++k) {
    const int h = l + 64*k;
    const float w0 = Wg[0*Hn+h], w1 = Wg[1*Hn+h], w2 = Wg[2*Hn+h], w3 = Wg[3*Hn+h];
    #pragma unroll
    for (int t = 0; t < 8; ++t) {
      float v = xb[t*Hn + h];
      xh[t*Hn + h] = (f16)v;
      a0 += v*w0; a1 += v*w1; a2 += v*w2; a3 += v*w3;
    }
  }
  #pragma unroll
  for (int o = 32; o > 0; o >>= 1) {
    a0 += __shfl_down(a0,o); a1 += __shfl_down(a1,o);
    a2 += __shfl_down(a2,o); a3 += __shfl_down(a3,o);
  }
  if (l == 0) { pacc[w][0]=a0; pacc[w][1]=a1; pacc[w][2]=a2; pacc[w][3]=a3; }
  __syncthreads();
  if (tid == 0) {
    float lg[4];
    #pragma unroll
    for (int e = 0; e < 4; ++e)
      lg[e] = (pacc[0][e]+pacc[1][e]+pacc[2][e]+pacc[3][e]) * (1.0f/Tn);
    float m = fmaxf(fmaxf(lg[0],lg[1]), fmaxf(lg[2],lg[3]));
    float p[4]; float s = 0.f;
    #pragma unroll
    for (int e = 0; e < 4; ++e) { p[e] = expf(lg[e]-m); s += p[e]; }
    float inv = 1.f/s;
    #pragma unroll
    for (int e = 0; e < 4; ++e) { p[e] *= inv; wsf[b*4+e] = p[e]; }
    int i1 = 0;
    #pragma unroll
    for (int e = 1; e < 4; ++e) if (p[e] > p[i1]) i1 = e;
    int i2 = (i1 == 0) ? 1 : 0;
    #pragma unroll
    for (int e = 0; e < 4; ++e) if (e != i1 && p[e] > p[i2]) i2 = e;
    int idx[2] = {i1, i2};
    #pragma unroll
    for (int k = 0; k < 2; ++k) {
      int r = 2*b + k;
      float pv = p[idx[k]];
      wsf[512 + r] = pv;
      route[r] = idx[k];
      out[SCORES_OFF + r] = pv;
      out[ROUTE_OFF  + r] = (float)idx[k];
      out[BIDX_OFF   + r] = (float)r;
    }
  }
}

__global__ __launch_bounds__(64) void loss_kernel(
    const float* __restrict__ wsf, float* __restrict__ out)
{
  const int l = threadIdx.x;
  float i0=0.f,i1=0.f,i2=0.f,i3=0.f;
  for (int b = l; b < Bn; b += 64) {
    i0 += wsf[b*4+0]; i1 += wsf[b*4+1]; i2 += wsf[b*4+2]; i3 += wsf[b*4+3];
  }
  #pragma unroll
  for (int o = 32; o > 0; o >>= 1) {
    i0 += __shfl_down(i0,o); i1 += __shfl_down(i1,o);
    i2 += __shfl_down(i2,o); i3 += __shfl_down(i3,o);
  }
  if (l == 0) {
    float mean = 0.25f*(i0+i1+i2+i3);
    float d0=i0-mean, d1=i1-mean, d2=i2-mean, d3=i3-mean;
    float var = (d0*d0+d1*d1+d2*d2+d3*d3) * (1.f/3.f);
    out[LOSS_OFF] = var / (mean*mean);
  }
}

// grp: [0]=nt4; tiles at [8+3i]={e,bstart,nb<=4}; blist at [384..639]
__global__ __launch_bounds__(64) void group_kernel(
    const int* __restrict__ route, int* __restrict__ grp)
{
  const int l = threadIdx.x;
  int cnt = 0;
  if (l < 4) { for (int r = 0; r < Rn; ++r) cnt += (route[r] == l); }
  int c0 = __shfl(cnt, 0), c1 = __shfl(cnt, 1), c2 = __shfl(cnt, 2), c3 = __shfl(cnt, 3);
  int off = (l >= 1 ? c0 : 0) + (l >= 2 ? c1 : 0) + (l >= 3 ? c2 : 0);
  if (l < 4) {
    int p = off;
    for (int r = 0; r < Rn; ++r) if (route[r] == l) grp[384 + p++] = r;
  }
  if (l == 0) {
    int cs[4] = {c0, c1, c2, c3};
    int os[4] = {0, c0, c0+c1, c0+c1+c2};
    int nt4 = 0;
    for (int e = 0; e < 4; ++e) {
      for (int s = 0; s < cs[e]; s += 4) {
        int nb = cs[e] - s; if (nb > 4) nb = 4;
        grp[8+nt4*3+0] = e; grp[8+nt4*3+1] = os[e]+s; grp[8+nt4*3+2] = nb;
        ++nt4;
      }
    }
    grp[0] = nt4;
  }
}

// Merged transpose+convert for W1 and W2: flat grid of 64x64 tiles.
__global__ __launch_bounds__(256) void transcvt_kernel(
    const float* __restrict__ W1s, const float* __restrict__ W2s,
    f16* __restrict__ d1, f16* __restrict__ d2)
{
  __shared__ f16 t[64][74];
  int bid = blockIdx.x;
  const float* s; f16* d; int R, C, rc;
  if (bid < 2304) { s = W1s; d = d1; R = Hn; C = Fn; rc = bid; }
  else            { s = W2s; d = d2; R = Fn; C = Hn; rc = bid - 2304; }
  const int e = rc / 576; rc -= e*576;
  const int nx = C >> 6;
  const int cy = rc / nx, cx = rc - cy*nx;
  const int r0 = cy*64, c0 = cx*64;
  s += (size_t)e*R*C;
  d += (size_t)e*R*C;
  const int tid = threadIdx.x;
  const int i  = tid >> 2;
  const int j0 = (tid & 3) * 16;
  #pragma unroll
  for (int q = 0; q < 16; q += 4) {
    float4 v = *(const float4*)(s + (size_t)(r0+i)*C + c0 + j0 + q);
    t[i][j0+q+0]=(f16)v.x; t[i][j0+q+1]=(f16)v.y; t[i][j0+q+2]=(f16)v.z; t[i][j0+q+3]=(f16)v.w;
  }
  __syncthreads();
  f16 o[16];
  #pragma unroll
  for (int q = 0; q < 16; ++q) o[q] = t[j0+q][i];
  *(uint4*)(d + (size_t)(c0+i)*R + r0 + j0)     = *(uint4*)&o[0];
  *(uint4*)(d + (size_t)(c0+i)*R + r0 + j0 + 8) = *(uint4*)&o[8];
}

// ---------------------------------------------------------------------------
// Grouped GEMM: BM=128 (4-beam), BK=32, wave-tile 64x64 (MI=NI=4).
// NBUF=3, depth-2 prefetch, counted vmcnt(NLD) per tile (never 0 mid-loop).
// Per tile: {8 ds_read ; NLD gloads for k+2 ; bar ; lgkm0 ; 16 MFMA ;
//            vmcnt(NLD) ; bar}.  2 blocks/CU (LDS <= 72KB).
// g1: BN=256, 8 waves.  g2: BN=128, 4 waves.
// ---------------------------------------------------------------------------
template<int KD, int ND, int BN, int NWAVE, bool G1>
__global__ __launch_bounds__(NWAVE*64, G1 ? 4 : 2) void gemm_kernel(
    const f16* __restrict__ A16, const f16* __restrict__ B16,
    const float* __restrict__ bias, f16* __restrict__ oh,
    float* __restrict__ of, const int* __restrict__ grp,
    const float* __restrict__ wsf)
{
  constexpr int NWY  = BN / 64;
  constexpr int NY   = ND / BN;
  constexpr int NT   = KD / 32;
  constexpr int NTHR = NWAVE * 64;
  constexpr int GL_A = 512 / NTHR;          // A 16B-units per thread (1 or 2)
  constexpr int GL_B = (BN*4) / NTHR;       // B units per thread (2)
  constexpr int NLD  = GL_A + GL_B;
  constexpr int BUFSZ = 8192 + BN*64;       // A[128][64B] + B[BN][64B]
  constexpr int TPR  = NWAVE * 2;           // epilogue rows per iter
  static_assert(NT % 3 == 0, "NT%3");

  const int ntiles = grp[0];
  const int tix = blockIdx.x / NY;
  const int ny  = blockIdx.x % NY;
  if (tix >= ntiles) return;
  const int e      = grp[8+tix*3+0];
  const int bstart = grp[8+tix*3+1];
  const int nb     = grp[8+tix*3+2];
  const int n0     = ny * BN;
  const int tid    = threadIdx.x;
  const int lane   = tid & 63;
  const int w      = tid >> 6;

  extern __shared__ __align__(16) char smem[];

  // ---- staging sources: LDS unit (row,u) holds global unit u^((row>>1)&3) ----
  const f16* asrc[GL_A];
  #pragma unroll
  for (int i = 0; i < GL_A; ++i) {
    const int U   = w*(GL_A*64) + i*64 + lane;
    const int row = U >> 2;
    const int gu  = (U & 3) ^ ((U >> 3) & 3);
    int slot = row >> 5; if (slot >= nb) slot = nb - 1;
    const int beam = grp[384 + bstart + slot];
    const size_t rbase = (G1 ? (size_t)(beam>>1)*Tn : (size_t)beam*Tn) + (row & 31);
    asrc[i] = A16 + rbase*(size_t)KD + gu*8;
  }
  const f16* bsrc[GL_B];
  #pragma unroll
  for (int i = 0; i < GL_B; ++i) {
    const int U   = w*(GL_B*64) + i*64 + lane;
    const int row = U >> 2;
    const int gu  = (U & 3) ^ ((U >> 3) & 3);
    bsrc[i] = B16 + (size_t)e*ND*KD + (size_t)(n0 + row)*KD + gu*8;
  }

  // ---- fragment geometry ----
  const int wm = w / NWY, wn = w % NWY;
  const int lr = lane & 15, lk = lane >> 4;
  const int rowA0 = wm*64;
  const int rowB0 = wn*64;
  const int ub = (lk ^ ((lr >> 1) & 3)) << 4;

  f32x4 acc[4][4];
  #pragma unroll
  for (int i=0;i<4;++i)
    #pragma unroll
    for (int j=0;j<4;++j) acc[i][j] = (f32x4){0.f,0.f,0.f,0.f};

  auto STAGE = [&](int bsel, int kt2) {
    char* Ad = smem + bsel*BUFSZ + (w*(GL_A*64))*16;
    #pragma unroll
    for (int i = 0; i < GL_A; ++i) GLOAD16(asrc[i] + kt2*32, Ad + i*1024);
    char* Bd = smem + bsel*BUFSZ + 8192 + (w*(GL_B*64))*16;
    #pragma unroll
    for (int i = 0; i < GL_B; ++i) GLOAD16(bsrc[i] + kt2*32, Bd + i*1024);
  };

  auto TILE = [&](int k, int b, bool dost, int vmc) {
    const char* Ab = smem + b*BUFSZ;
    const char* Bb = Ab + 8192;
    f16x8 af[4], bf[4];
    #pragma unroll
    for (int mi=0;mi<4;++mi)
      af[mi] = *(const f16x8*)(Ab + (rowA0 + mi*16 + lr)*64 + ub);
    #pragma unroll
    for (int ni=0;ni<4;++ni)
      bf[ni] = *(const f16x8*)(Bb + (rowB0 + ni*16 + lr)*64 + ub);
    if (dost) STAGE((b+2)%3, k+2);
    __builtin_amdgcn_sched_barrier(0);
    __builtin_amdgcn_s_barrier();
    __builtin_amdgcn_sched_barrier(0);
    asm volatile("s_waitcnt lgkmcnt(0)" ::: "memory");
    __builtin_amdgcn_sched_barrier(0);
    __builtin_amdgcn_s_setprio(1);
    #pragma unroll
    for (int mi=0;mi<4;++mi)
      #pragma unroll
      for (int ni=0;ni<4;++ni)
        acc[mi][ni] = __builtin_amdgcn_mfma_f32_16x16x32_f16(af[mi], bf[ni], acc[mi][ni], 0, 0, 0);
    __builtin_amdgcn_s_setprio(0);
    if (vmc > 0)       asm volatile("s_waitcnt vmcnt(%0)" :: "i"(NLD) : "memory");
    else if (vmc == 0) asm volatile("s_waitcnt vmcnt(0)" ::: "memory");
    __builtin_amdgcn_sched_barrier(0);
    __builtin_amdgcn_s_barrier();
    __builtin_amdgcn_sched_barrier(0);
  };

  // prologue: stage tiles 0,1; certify tile 0 (leave tile 1 in flight)
  STAGE(0, 0);
  STAGE(1, 1);
  asm volatile("s_waitcnt vmcnt(%0)" :: "i"(NLD) : "memory");
  __builtin_amdgcn_sched_barrier(0);
  __builtin_amdgcn_s_barrier();
  __builtin_amdgcn_sched_barrier(0);

  {
    int b = 0;
    for (int k = 0; k < NT-2; ++k) {
      TILE(k, b, true, NLD);          // stages k+2, certifies k+1
      b = (b+1)%3;
    }
    TILE(NT-2, b, false, 0);          // certifies NT-1
    b = (b+1)%3;
    TILE(NT-1, b, false, -1);
  }

  // ---- epilogue: 128 rows through swizzled LDS ----
  const int nvalid = nb * Tn;
  char* cst = smem;
  float bvals[4];
  if (G1) {
    #pragma unroll
    for (int ni=0;ni<4;++ni) bvals[ni] = bias[e*ND + n0 + rowB0 + ni*16 + lr];
  }
  #pragma unroll
  for (int mi=0;mi<4;++mi){
    #pragma unroll
    for (int j=0;j<4;++j){
      const int m = rowA0 + mi*16 + (lane>>4)*4 + j;
      const int m7 = m & 7;
      #pragma unroll
      for (int ni=0;ni<4;++ni){
        const int n = rowB0 + ni*16 + lr;
        if (G1) {
          float v = acc[mi][ni][j] + bvals[ni];
          *(f16*)(cst + m*512 + (((n>>3)^m7)<<4) + (n&7)*2) = (f16)fast_gelu(v);
        } else {
          *(float*)(cst + m*512 + (((n>>2)^m7)<<4) + (n&3)*4) = acc[mi][ni][j];
        }
      }
    }
  }
  __syncthreads();
  {
    const int u  = tid & 31;
    const int tr = tid >> 5;
    float4 b4;
    if (!G1) b4 = *(const float4*)(bias + e*ND + n0 + u*4);
    #pragma unroll
    for (int it = 0; it < 128/TPR; ++it) {
      const int rl = it*TPR + tr;
      if (rl < nvalid) {
        const int beam = grp[384 + bstart + (rl>>5)];
        if (G1) {
          uint4 v = *(const uint4*)(cst + rl*512 + (((u&24)|((u&7)^(rl&7)))<<4));
          *(uint4*)(oh + ((size_t)beam*Tn + (rl&31))*(size_t)ND + n0 + u*8) = v;
        } else {
          const float sc = wsf[512 + beam];
          float4 v = *(const float4*)(cst + rl*512 + (((u&24)|((u&7)^(rl&7)))<<4));
          v.x = (v.x + b4.x)*sc; v.y = (v.y + b4.y)*sc;
          v.z = (v.z + b4.z)*sc; v.w = (v.w + b4.w)*sc;
          *(float4*)(of + ((size_t)beam*Tn + (rl&31))*(size_t)Hn + n0 + u*4) = v;
        }
      }
    }
  }
}

extern "C" void kernel_launch(void* const* d_in, const int* in_sizes, int n_in,
                              void* d_out, int out_size, void* d_ws, size_t ws_size,
                              hipStream_t stream)
{
  const float* x  = (const float*)d_in[0];
  const float* Wg = (const float*)d_in[1];
  const float* W1 = (const float*)d_in[2];
  const float* b1 = (const float*)d_in[3];
  const float* W2 = (const float*)d_in[4];
  const float* b2 = (const float*)d_in[5];
  float* out = (float*)d_out;
  char* ws = (char*)d_ws;
  float* wsf  = (float*)(ws + WS_WSF);
  int*   route= (int*)(ws + WS_ROUTE);
  int*   grp  = (int*)(ws + WS_GRP);
  f16*   x16  = (f16*)(ws + WS_X16);
  f16*   w1t  = (f16*)(ws + WS_W1T);
  f16*   w2t  = (f16*)(ws + WS_W2T);
  f16*   h1   = (f16*)(ws + WS_H1);

  gate_kernel<<<Bn, 256, 0, stream>>>(x, Wg, out, wsf, route, x16);
  group_kernel<<<1, 64, 0, stream>>>(route, grp);
  loss_kernel<<<1, 64, 0, stream>>>(wsf, out);
  transcvt_kernel<<<4608, 256, 0, stream>>>(W1, W2, w1t, w2t);

  auto g1 = gemm_kernel<Hn, Fn, 256, 8, true>;    // 512 thr, LDS 72KB, 2 blk/CU
  auto g2 = gemm_kernel<Fn, Hn, 128, 4, false>;   // 256 thr, LDS 64KB, 2 blk/CU
  const int sm1 = 3*(8192 + 256*64);      // 73728
  const int sm2 = 65536;                  // bufs 36864 + cst 64KB window
  hipFuncSetAttribute((const void*)g1, hipFuncAttributeMaxDynamicSharedMemorySize, sm1);
  hipFuncSetAttribute((const void*)g2, hipFuncAttributeMaxDynamicSharedMemorySize, sm2);
  g1<<<MAXT4*12, 512, sm1, stream>>>(x16, w1t, b1, h1, nullptr, grp, wsf);
  g2<<<MAXT4*6,  256, sm2, stream>>>(h1, w2t, b2, nullptr, out, grp, wsf);
}